// Round 1
// baseline (4736.337 us; speedup 1.0000x reference)
//
#include <hip/hip_runtime.h>
#include <hip/hip_bf16.h>
#include <cstdio>

typedef __hip_bfloat16 bf16;
typedef __attribute__((ext_vector_type(8))) short s16x8;
typedef __attribute__((ext_vector_type(4))) float f32x4;

// Problem constants
#define TT 55
#define BB 512
#define CC 512
#define DD 512
#define KK 64

struct Seg {
  float* dst;          // destination base
  long   ldd;          // row stride (elements)
  int    col_begin;    // inclusive (GEMM N space)
  int    col_end;      // exclusive
  int    add;          // 1 = +=, 0 = overwrite
  const float* bias;   // indexed by (col - col_begin), may be null
};
struct SegList { Seg s[6]; int n; };

// ---------------- GEMM: C[seg] (+)= A[M x K] * B^T[N x K], bf16 in, fp32 out
// grid = (M/64, N/64), block = 256 (4 waves). 64x64 tile, BK=64.
__global__ __launch_bounds__(256) void gemm_bf16(
    const bf16* __restrict__ A, long lda,
    const bf16* __restrict__ B, long ldb,
    int K, SegList segs)
{
  __shared__ __align__(16) bf16 As[64][72];  // +8 pad: 2-way LDS conflict only
  __shared__ __align__(16) bf16 Bs[64][72];
  const int tid  = threadIdx.x;
  const int wave = tid >> 6, lane = tid & 63;
  const int q = lane >> 4, mm = lane & 15;
  const long m0 = (long)blockIdx.x * 64;
  const long n0 = (long)blockIdx.y * 64;

  const int lrow = tid >> 3;        // 0..31
  const int lcol = (tid & 7) << 3;  // 0..56 step 8
  const bf16* Ab = A + m0 * lda;
  const bf16* Bb = B + n0 * ldb;

  f32x4 acc0 = {0.f,0.f,0.f,0.f}, acc1 = acc0, acc2 = acc0, acc3 = acc0;

  for (int k0 = 0; k0 < K; k0 += 64) {
    *(float4*)(&As[lrow][lcol])      = *(const float4*)(Ab + (long)lrow*lda + k0 + lcol);
    *(float4*)(&As[lrow+32][lcol])   = *(const float4*)(Ab + (long)(lrow+32)*lda + k0 + lcol);
    *(float4*)(&Bs[lrow][lcol])      = *(const float4*)(Bb + (long)lrow*ldb + k0 + lcol);
    *(float4*)(&Bs[lrow+32][lcol])   = *(const float4*)(Bb + (long)(lrow+32)*ldb + k0 + lcol);
    __syncthreads();
#pragma unroll
    for (int kk = 0; kk < 64; kk += 32) {
      s16x8 af = *(const s16x8*)(&As[wave*16 + mm][kk + q*8]);
      s16x8 b0 = *(const s16x8*)(&Bs[ 0 + mm][kk + q*8]);
      s16x8 b1 = *(const s16x8*)(&Bs[16 + mm][kk + q*8]);
      s16x8 b2 = *(const s16x8*)(&Bs[32 + mm][kk + q*8]);
      s16x8 b3 = *(const s16x8*)(&Bs[48 + mm][kk + q*8]);
      acc0 = __builtin_amdgcn_mfma_f32_16x16x32_bf16(af, b0, acc0, 0,0,0);
      acc1 = __builtin_amdgcn_mfma_f32_16x16x32_bf16(af, b1, acc1, 0,0,0);
      acc2 = __builtin_amdgcn_mfma_f32_16x16x32_bf16(af, b2, acc2, 0,0,0);
      acc3 = __builtin_amdgcn_mfma_f32_16x16x32_bf16(af, b3, acc3, 0,0,0);
    }
    __syncthreads();
  }

  // segment lookup (uniform per block; segments sorted by col_begin, 64-aligned)
  Seg sg = segs.s[0];
  for (int i = 1; i < segs.n; ++i)
    if ((int)n0 >= segs.s[i].col_begin) sg = segs.s[i];

#pragma unroll
  for (int ni = 0; ni < 4; ++ni) {
    f32x4 a = (ni==0) ? acc0 : (ni==1) ? acc1 : (ni==2) ? acc2 : acc3;
    int col  = (int)n0 + ni*16 + mm;
    int dcol = col - sg.col_begin;
    float bv = sg.bias ? sg.bias[dcol] : 0.0f;
#pragma unroll
    for (int r = 0; r < 4; ++r) {
      long row = m0 + wave*16 + q*4 + r;   // C/D layout: col=lane&15, row=q*4+reg
      float* p = sg.dst + row * sg.ldd + dcol;
      float v = a[r] + bv;
      if (sg.add) *p = *p + v; else *p = v;
    }
  }
}

// ---------------- per-(step,layer) elementwise cell update
__device__ inline float sigm(float x){ return 1.0f/(1.0f + __expf(-x)); }

__global__ __launch_bounds__(256) void cell_ew(
    const float* __restrict__ gate,  // [512][2048] complete gate accum
    const float* __restrict__ gr,    // [512][64]
    const float* __restrict__ u0,    // prev-step h0@Wl0, may be null
    const float* __restrict__ u1,    // prev-step h1@Wl1, may be null
    float* __restrict__ c,           // [512][512] in-place
    float* __restrict__ d,           // [512][64] in-place
    const float* __restrict__ wd,    // [64][512]
    bf16* __restrict__ hout, long ldh)
{
  const int b = blockIdx.x, tid = threadIdx.x;
  __shared__ float dn[64];
  if (tid < 64) {
    float g = gr[b*64 + tid];
    if (u0) g += (1.0f/3.0f) * u0[b*64 + tid];
    if (u1) g += (1.0f/3.0f) * u1[b*64 + tid];
    float r  = sigm(g);
    float dv = r * d[b*64 + tid];
    d[b*64 + tid] = dv;
    dn[tid] = dv;
  }
  __syncthreads();
  const float* g = gate + (long)b * 2048;
  for (int n = tid; n < 512; n += 256) {
    float fv = sigm(g[n]);
    float iv = sigm(g[512 + n]);
    float ov = sigm(g[1024 + n]);
    float cb = tanhf(g[1536 + n]);
    float mv = 0.0f;
#pragma unroll
    for (int k = 0; k < 64; ++k) mv += dn[k] * wd[k*512 + n];
    float cv = fv * c[b*512 + n] + iv * cb + tanhf(mv);
    c[b*512 + n] = cv;
    hout[(long)b*ldh + n] = __float2bfloat16(ov * tanhf(cv));
  }
}

// ---------------- setup kernels
// dst[n*K + k] = (bf16) src[k*srow + n]
__global__ void k_tpose(const float* __restrict__ src, long srow,
                        bf16* __restrict__ dst, int K, long total)
{
  long idx = (long)blockIdx.x * 256 + threadIdx.x;
  if (idx >= total) return;
  long n = idx / K;
  long k = idx - n * K;
  dst[idx] = __float2bfloat16(src[k * srow + n]);
}

// xb[(t*512+b)*512+c] = x[(b*55+t)*512+c]
__global__ void k_xconv(const float* __restrict__ x, bf16* __restrict__ xb)
{
  long i = (long)blockIdx.x * 256 + threadIdx.x;
  if (i >= (long)TT*BB*CC) return;
  int cc = (int)(i & 511);
  long r = i >> 9;
  int t = (int)(r / BB), b = (int)(r - (long)t*BB);
  xb[i] = __float2bfloat16(x[((long)b*TT + t)*CC + cc]);
}

__global__ void k_bias(const float* b0,const float* b1,const float* b2,
                       const float* b3,const float* b4,const float* b5,
                       float* out)
{
  int i = blockIdx.x*256 + threadIdx.x;
  if (i < 2048)      out[i] = b0[i] + b1[i];
  else if (i < 4096) out[i] = b2[i-2048] + b3[i-2048];
  else if (i < 6144) out[i] = b4[i-4096] + b5[i-4096];
}

__global__ void k_dinit(const float* __restrict__ keys, float* __restrict__ d)
{
  int i = blockIdx.x*256 + threadIdx.x;
  if (i < 3*BB*KK) d[i] = keys[i % (BB*KK)];
}

// ---------------- host
extern "C" void kernel_launch(void* const* d_in, const int* in_sizes, int n_in,
                              void* d_out, int out_size, void* d_ws, size_t ws_size,
                              hipStream_t stream)
{
  const float* inputs    = (const float*)d_in[0];
  const float* init_keys = (const float*)d_in[1];
  const float* wx_w[3] = {(const float*)d_in[2],  (const float*)d_in[8],  (const float*)d_in[14]};
  const float* wx_b[3] = {(const float*)d_in[3],  (const float*)d_in[9],  (const float*)d_in[15]};
  const float* wh_w[3] = {(const float*)d_in[4],  (const float*)d_in[10], (const float*)d_in[16]};
  const float* wh_b[3] = {(const float*)d_in[5],  (const float*)d_in[11], (const float*)d_in[17]};
  const float* wr_w[3] = {(const float*)d_in[6],  (const float*)d_in[12], (const float*)d_in[18]};
  const float* wl_w[3] = {(const float*)d_in[7],  (const float*)d_in[13], (const float*)d_in[19]};
  const float* wd_w   = (const float*)d_in[20];
  const float* proj_w = (const float*)d_in[21];
  const float* proj_b = (const float*)d_in[22];
  float* out = (float*)d_out;

  char* wsp = (char*)d_ws;
  size_t used = 0;
  auto alloc = [&](size_t bytes) {
    char* p = wsp + used;
    used += (bytes + 255) & ~(size_t)255;
    return p;
  };
  bf16* xb    = (bf16*)alloc((size_t)TT*BB*CC*2);        // [t][b][c]
  bf16* BXT   = (bf16*)alloc((size_t)6336*512*2);        // x-driven  B^T
  bf16* BG0T  = (bf16*)alloc((size_t)6336*512*2);        // h0-driven B^T
  bf16* BG1T  = (bf16*)alloc((size_t)4224*512*2);        // h1-driven B^T
  bf16* BG2T  = (bf16*)alloc((size_t)2048*512*2);        // h2-driven B^T
  bf16* projT = (bf16*)alloc((size_t)512*1536*2);
  bf16* Hall  = (bf16*)alloc((size_t)BB*TT*1536*2);      // [b][t][3*512]
  float* accg = (float*)alloc((size_t)2*3*BB*2048*4);    // [parity][l][b][2048]
  float* accr = (float*)alloc((size_t)2*3*BB*64*4);      // [parity][l][b][64]
  float* ubuf = (float*)alloc((size_t)2*2*BB*64*4);      // [parity][j][b][64]
  float* cbuf = (float*)alloc((size_t)3*BB*DD*4);
  float* dbuf = (float*)alloc((size_t)3*BB*KK*4);
  float* biasg= (float*)alloc((size_t)3*2048*4);
  if (used > ws_size) { fprintf(stderr, "ws too small: need %zu have %zu\n", used, ws_size); return; }

  const long SZG = (long)BB*2048;
  const long SZR = (long)BB*64;
  const long LDH = (long)TT*1536;  // Hall row stride for a fixed b

  // ---- setup
  {
    long tot = (long)TT*BB*CC;
    k_xconv<<<dim3((tot + 255)/256), 256, 0, stream>>>(inputs, xb);
  }
  auto tp = [&](const float* src, long row_off, long srow, bf16* dstbase, long colbase, int N, int K){
    long total = (long)N*K;
    k_tpose<<<dim3((total + 255)/256), 256, 0, stream>>>(src + row_off*srow, srow, dstbase + colbase*K, K, total);
  };
  // BXT cols: [Wx0|Wr0|Wx1|Wr1|Wx2|Wr2] (first C=512 rows of each)
  tp(wx_w[0],0,2048, BXT,0,2048,512);   tp(wr_w[0],0,64, BXT,2048,64,512);
  tp(wx_w[1],0,2048, BXT,2112,2048,512);tp(wr_w[1],0,64, BXT,4160,64,512);
  tp(wx_w[2],0,2048, BXT,4224,2048,512);tp(wr_w[2],0,64, BXT,6272,64,512);
  // BG0T cols: [Wx1.h0|Wr1.h0|Wx2.h0|Wr2.h0|Wh0|Wl0]
  tp(wx_w[1],512,2048, BG0T,0,2048,512);   tp(wr_w[1],512,64, BG0T,2048,64,512);
  tp(wx_w[2],512,2048, BG0T,2112,2048,512);tp(wr_w[2],512,64, BG0T,4160,64,512);
  tp(wh_w[0],0,2048,   BG0T,4224,2048,512);tp(wl_w[0],0,64,   BG0T,6272,64,512);
  // BG1T cols: [Wx2.h1|Wr2.h1|Wh1|Wl1]
  tp(wx_w[2],1024,2048, BG1T,0,2048,512);  tp(wr_w[2],1024,64, BG1T,2048,64,512);
  tp(wh_w[1],0,2048,    BG1T,2112,2048,512);tp(wl_w[1],0,64,   BG1T,4160,64,512);
  // BG2T: [Wh2]
  tp(wh_w[2],0,2048, BG2T,0,2048,512);
  // projT
  tp(proj_w,0,512, projT,0,512,1536);

  k_bias<<<dim3(24),256,0,stream>>>(wx_b[0],wh_b[0],wx_b[1],wh_b[1],wx_b[2],wh_b[2], biasg);
  hipMemsetAsync(ubuf, 0, (size_t)2*2*BB*64*4, stream);
  hipMemsetAsync(cbuf, 0, (size_t)3*BB*DD*4, stream);
  k_dinit<<<dim3((3*BB*KK + 255)/256),256,0,stream>>>(init_keys, dbuf);

  auto gemm = [&](const bf16* A, long lda, const bf16* B, long ldb, int M, int N, int K, SegList segs){
    gemm_bf16<<<dim3(M/64, N/64), 256, 0, stream>>>(A, lda, B, ldb, K, segs);
  };

  auto launch_I = [&](int t){ // acc(t) <- x_t-driven parts + biases
    int p = t & 1;
    SegList s{}; s.n = 6;
    s.s[0] = { accg + ((long)p*3+0)*SZG, 2048,    0, 2048, 0, biasg + 0    };
    s.s[1] = { accr + ((long)p*3+0)*SZR,   64, 2048, 2112, 0, nullptr      };
    s.s[2] = { accg + ((long)p*3+1)*SZG, 2048, 2112, 4160, 0, biasg + 2048 };
    s.s[3] = { accr + ((long)p*3+1)*SZR,   64, 4160, 4224, 0, nullptr      };
    s.s[4] = { accg + ((long)p*3+2)*SZG, 2048, 4224, 6272, 0, biasg + 4096 };
    s.s[5] = { accr + ((long)p*3+2)*SZR,   64, 6272, 6336, 0, nullptr      };
    gemm(xb + (long)t*BB*CC, 512, BXT, 512, 512, 6336, 512, s);
  };
  auto launch_G0 = [&](int t){ // consumers of fresh h0(t)
    int p = t & 1, p1 = (t+1) & 1;
    SegList s{}; s.n = 6;
    s.s[0] = { accg + ((long)p *3+1)*SZG, 2048,    0, 2048, 1, nullptr };
    s.s[1] = { accr + ((long)p *3+1)*SZR,   64, 2048, 2112, 1, nullptr };
    s.s[2] = { accg + ((long)p *3+2)*SZG, 2048, 2112, 4160, 1, nullptr };
    s.s[3] = { accr + ((long)p *3+2)*SZR,   64, 4160, 4224, 1, nullptr };
    s.s[4] = { accg + ((long)p1*3+0)*SZG, 2048, 4224, 6272, 1, nullptr };  // Wh0 -> gate0(t+1)
    s.s[5] = { ubuf + ((long)p *2+0)*SZR,   64, 6272, 6336, 0, nullptr };  // u0 = h0@Wl0
    gemm(Hall + (long)t*1536 + 0, LDH, BG0T, 512, 512, 6336, 512, s);
  };
  auto launch_G1 = [&](int t){
    int p = t & 1, p1 = (t+1) & 1;
    SegList s{}; s.n = 4;
    s.s[0] = { accg + ((long)p *3+2)*SZG, 2048,    0, 2048, 1, nullptr };
    s.s[1] = { accr + ((long)p *3+2)*SZR,   64, 2048, 2112, 1, nullptr };
    s.s[2] = { accg + ((long)p1*3+1)*SZG, 2048, 2112, 4160, 1, nullptr };  // Wh1 -> gate1(t+1)
    s.s[3] = { ubuf + ((long)p *2+1)*SZR,   64, 4160, 4224, 0, nullptr };  // u1 = h1@Wl1
    gemm(Hall + (long)t*1536 + 512, LDH, BG1T, 512, 512, 4224, 512, s);
  };
  auto launch_G2 = [&](int t){
    int p1 = (t+1) & 1;
    SegList s{}; s.n = 1;
    s.s[0] = { accg + ((long)p1*3+2)*SZG, 2048, 0, 2048, 1, nullptr };     // Wh2 -> gate2(t+1)
    gemm(Hall + (long)t*1536 + 1024, LDH, BG2T, 512, 512, 2048, 512, s);
  };
  auto launch_E = [&](int t, int l){
    int p = t & 1, p1 = (t+1) & 1;  // p1 == (t-1)&1: previous step's u parity
    const float* u0 = (l >= 1) ? (ubuf + ((long)p1*2+0)*SZR) : nullptr;
    const float* u1 = (l >= 2) ? (ubuf + ((long)p1*2+1)*SZR) : nullptr;
    cell_ew<<<dim3(512), 256, 0, stream>>>(
        accg + ((long)p*3+l)*SZG, accr + ((long)p*3+l)*SZR, u0, u1,
        cbuf + (long)l*BB*DD, dbuf + (long)l*BB*KK, wd_w,
        Hall + (long)t*1536 + (long)l*512, LDH);
  };

  // ---- recurrence
  launch_I(0);
  for (int t = 0; t < TT; ++t) {
    if (t + 1 < TT) launch_I(t + 1);
    launch_E(t, 0); launch_G0(t);
    launch_E(t, 1); launch_G1(t);
    launch_E(t, 2); launch_G2(t);
  }

  // ---- projection: out[b][t][:] = Hall[b][t][:] @ proj + proj_b
  {
    SegList s{}; s.n = 1;
    s.s[0] = { out, 512, 0, 512, 0, proj_b };
    gemm(Hall, 1536, projT, 1536, BB*TT, 512, 1536, s);
  }
}

// Round 2
// 3741.179 us; speedup vs baseline: 1.2660x; 1.2660x over previous
//
#include <hip/hip_runtime.h>
#include <hip/hip_bf16.h>
#include <cstdio>

typedef __hip_bfloat16 bf16;
typedef __attribute__((ext_vector_type(8))) short s16x8;
typedef __attribute__((ext_vector_type(4))) float f32x4;

// Problem constants
#define TT 55
#define BB 512
#define CC 512
#define DD 512
#define KK 64
#define LDH ((long)TT*1536)

struct Seg {
  float* dst;          // destination base
  long   ldd;          // row stride (elements)
  int    col_begin;    // inclusive (GEMM N space), 64-aligned, sorted asc
  int    mode;         // 0 = store (+bias), 1 = atomicAdd
  const float* bias;   // indexed by (col - col_begin), may be null
};
struct SegList { Seg s[6]; int n; };

struct GDesc {
  const bf16* A; const bf16* B;
  long lda, ldb;
  int mtiles, ntiles, tile_beg;
  SegList segs;
};
struct GArgs { GDesc g[4]; int ng; int K; };

// ---------------- batched GEMM: for each sub-problem, C[seg] (+)= A[MxK] * B^T[NxK]
// bf16 in, fp32 out. 64x64 tile, BK=64, block=256 (4 waves), 1-D grid over all tiles.
__global__ __launch_bounds__(256) void gemm_batched(GArgs args)
{
  __shared__ __align__(16) bf16 As[64][72];  // +8 pad
  __shared__ __align__(16) bf16 Bs[64][72];

  // which sub-gemm?
  int gi = 0;
  if (args.ng > 1 && (int)blockIdx.x >= args.g[1].tile_beg) gi = 1;
  if (args.ng > 2 && (int)blockIdx.x >= args.g[2].tile_beg) gi = 2;
  if (args.ng > 3 && (int)blockIdx.x >= args.g[3].tile_beg) gi = 3;
  const GDesc& g = args.g[gi];
  const int local = (int)blockIdx.x - g.tile_beg;
  const int nt = local % g.ntiles;
  const int mt = local / g.ntiles;

  const int tid  = threadIdx.x;
  const int wave = tid >> 6, lane = tid & 63;
  const int q = lane >> 4, mm = lane & 15;
  const long m0 = (long)mt * 64;
  const long n0 = (long)nt * 64;

  const int lrow = tid >> 3;        // 0..31
  const int lcol = (tid & 7) << 3;  // 0..56 step 8
  const bf16* Ab = g.A + m0 * g.lda;
  const bf16* Bb = g.B + n0 * g.ldb;
  const long lda = g.lda, ldb = g.ldb;
  const int K = args.K;

  f32x4 acc0 = {0.f,0.f,0.f,0.f}, acc1 = acc0, acc2 = acc0, acc3 = acc0;

  for (int k0 = 0; k0 < K; k0 += 64) {
    *(float4*)(&As[lrow][lcol])      = *(const float4*)(Ab + (long)lrow*lda + k0 + lcol);
    *(float4*)(&As[lrow+32][lcol])   = *(const float4*)(Ab + (long)(lrow+32)*lda + k0 + lcol);
    *(float4*)(&Bs[lrow][lcol])      = *(const float4*)(Bb + (long)lrow*ldb + k0 + lcol);
    *(float4*)(&Bs[lrow+32][lcol])   = *(const float4*)(Bb + (long)(lrow+32)*ldb + k0 + lcol);
    __syncthreads();
#pragma unroll
    for (int kk = 0; kk < 64; kk += 32) {
      s16x8 af = *(const s16x8*)(&As[wave*16 + mm][kk + q*8]);
      s16x8 b0 = *(const s16x8*)(&Bs[ 0 + mm][kk + q*8]);
      s16x8 b1 = *(const s16x8*)(&Bs[16 + mm][kk + q*8]);
      s16x8 b2 = *(const s16x8*)(&Bs[32 + mm][kk + q*8]);
      s16x8 b3 = *(const s16x8*)(&Bs[48 + mm][kk + q*8]);
      acc0 = __builtin_amdgcn_mfma_f32_16x16x32_bf16(af, b0, acc0, 0,0,0);
      acc1 = __builtin_amdgcn_mfma_f32_16x16x32_bf16(af, b1, acc1, 0,0,0);
      acc2 = __builtin_amdgcn_mfma_f32_16x16x32_bf16(af, b2, acc2, 0,0,0);
      acc3 = __builtin_amdgcn_mfma_f32_16x16x32_bf16(af, b3, acc3, 0,0,0);
    }
    __syncthreads();
  }

  // segment lookup (uniform per block; segments sorted by col_begin, 64-aligned)
  Seg sg = g.segs.s[0];
  for (int i = 1; i < g.segs.n; ++i)
    if ((int)n0 >= g.segs.s[i].col_begin) sg = g.segs.s[i];

#pragma unroll
  for (int ni = 0; ni < 4; ++ni) {
    f32x4 a = (ni==0) ? acc0 : (ni==1) ? acc1 : (ni==2) ? acc2 : acc3;
    int col  = (int)n0 + ni*16 + mm;
    int dcol = col - sg.col_begin;
    float bv = sg.bias ? sg.bias[dcol] : 0.0f;
#pragma unroll
    for (int r = 0; r < 4; ++r) {
      long row = m0 + wave*16 + q*4 + r;   // C/D layout: col=lane&15, row=q*4+reg
      float* p = sg.dst + row * sg.ldd + dcol;
      if (sg.mode) atomicAdd(p, a[r]);
      else         *p = a[r] + bv;
    }
  }
}

// ---------------- batched cell update: up to 3 independent (step,layer) cells
struct CellDesc {
  const float* gate;   // [512][2048]
  const float* gr;     // [512][64]
  const float* u0;     // may be null
  const float* u1;     // may be null
  float* c;            // [512][512]
  float* d;            // [512][64]
  bf16*  hout;         // row stride LDH
};
struct CArgs { CellDesc e[3]; int n; };

__device__ inline float sigm(float x){ return 1.0f/(1.0f + __expf(-x)); }

__global__ __launch_bounds__(256) void cell_batched(CArgs a, const float* __restrict__ wd)
{
  const CellDesc e = a.e[blockIdx.y];
  const int tid = threadIdx.x;
  const int r0 = blockIdx.x * 8;   // 8 batch rows per block, grid.x = 64
  __shared__ float dn[8][64];

  for (int i = tid; i < 512; i += 256) {
    int r = i >> 6, k = i & 63;
    long idx = (long)(r0 + r)*64 + k;
    float gv = e.gr[idx];
    if (e.u0) gv += (1.0f/3.0f)*e.u0[idx];
    if (e.u1) gv += (1.0f/3.0f)*e.u1[idx];
    float rr = sigm(gv);
    float dv = rr * e.d[idx];
    e.d[idx] = dv;
    dn[r][k] = dv;
  }
  __syncthreads();

  // mv[n] = sum_k dn[r][k] * wd[k][n]; each thread: n = tid, tid+256, all 8 rows
  float accv[2][8] = {};
  for (int k = 0; k < 64; ++k) {
    float w0 = wd[k*512 + tid];
    float w1 = wd[k*512 + tid + 256];
#pragma unroll
    for (int r = 0; r < 8; ++r) {
      float dv = dn[r][k];
      accv[0][r] += dv * w0;
      accv[1][r] += dv * w1;
    }
  }

#pragma unroll
  for (int half = 0; half < 2; ++half) {
    int n = tid + half*256;
#pragma unroll
    for (int r = 0; r < 8; ++r) {
      long row = r0 + r;
      const float* gg = e.gate + row*2048;
      float fv = sigm(gg[n]);
      float iv = sigm(gg[512 + n]);
      float ov = sigm(gg[1024 + n]);
      float cb = tanhf(gg[1536 + n]);
      float cv = fv * e.c[row*512 + n] + iv * cb + tanhf(accv[half][r]);
      e.c[row*512 + n] = cv;
      e.hout[row*LDH + n] = __float2bfloat16(ov * tanhf(cv));
    }
  }
}

// ---------------- setup kernels
__global__ void k_tpose(const float* __restrict__ src, long srow,
                        bf16* __restrict__ dst, int K, long total)
{
  long idx = (long)blockIdx.x * 256 + threadIdx.x;
  if (idx >= total) return;
  long n = idx / K;
  long k = idx - n * K;
  dst[idx] = __float2bfloat16(src[k * srow + n]);
}

__global__ void k_xconv(const float* __restrict__ x, bf16* __restrict__ xb)
{
  long i = (long)blockIdx.x * 256 + threadIdx.x;
  if (i >= (long)TT*BB*CC) return;
  int cc = (int)(i & 511);
  long r = i >> 9;
  int t = (int)(r / BB), b = (int)(r - (long)t*BB);
  xb[i] = __float2bfloat16(x[((long)b*TT + t)*CC + cc]);
}

__global__ void k_bias(const float* b0,const float* b1,const float* b2,
                       const float* b3,const float* b4,const float* b5,
                       float* out)
{
  int i = blockIdx.x*256 + threadIdx.x;
  if (i < 2048)      out[i] = b0[i] + b1[i];
  else if (i < 4096) out[i] = b2[i-2048] + b3[i-2048];
  else if (i < 6144) out[i] = b4[i-4096] + b5[i-4096];
}

__global__ void k_dinit(const float* __restrict__ keys, float* __restrict__ d)
{
  int i = blockIdx.x*256 + threadIdx.x;
  if (i < 3*BB*KK) d[i] = keys[i % (BB*KK)];
}

// ---------------- host
extern "C" void kernel_launch(void* const* d_in, const int* in_sizes, int n_in,
                              void* d_out, int out_size, void* d_ws, size_t ws_size,
                              hipStream_t stream)
{
  const float* inputs    = (const float*)d_in[0];
  const float* init_keys = (const float*)d_in[1];
  const float* wx_w[3] = {(const float*)d_in[2],  (const float*)d_in[8],  (const float*)d_in[14]};
  const float* wx_b[3] = {(const float*)d_in[3],  (const float*)d_in[9],  (const float*)d_in[15]};
  const float* wh_w[3] = {(const float*)d_in[4],  (const float*)d_in[10], (const float*)d_in[16]};
  const float* wh_b[3] = {(const float*)d_in[5],  (const float*)d_in[11], (const float*)d_in[17]};
  const float* wr_w[3] = {(const float*)d_in[6],  (const float*)d_in[12], (const float*)d_in[18]};
  const float* wl_w[3] = {(const float*)d_in[7],  (const float*)d_in[13], (const float*)d_in[19]};
  const float* wd_w   = (const float*)d_in[20];
  const float* proj_w = (const float*)d_in[21];
  const float* proj_b = (const float*)d_in[22];
  float* out = (float*)d_out;

  char* wsp = (char*)d_ws;
  size_t used = 0;
  auto alloc = [&](size_t bytes) {
    char* p = wsp + used;
    used += (bytes + 255) & ~(size_t)255;
    return p;
  };
  bf16* xb    = (bf16*)alloc((size_t)TT*BB*CC*2);        // [t][b][c]
  bf16* BXT   = (bf16*)alloc((size_t)6336*512*2);        // x-driven  B^T
  bf16* BG0T  = (bf16*)alloc((size_t)6336*512*2);        // h0-driven B^T
  bf16* BG1T  = (bf16*)alloc((size_t)4224*512*2);        // h1-driven B^T
  bf16* BG2T  = (bf16*)alloc((size_t)2048*512*2);        // h2-driven B^T
  bf16* projT = (bf16*)alloc((size_t)512*1536*2);
  bf16* Hall  = (bf16*)alloc((size_t)BB*TT*1536*2);      // [b][t][3*512]
  float* accg = (float*)alloc((size_t)4*3*BB*2048*4);    // [slot][l][b][2048]
  float* accr = (float*)alloc((size_t)4*3*BB*64*4);      // [slot][l][b][64]
  float* ubuf = (float*)alloc((size_t)4*2*BB*64*4);      // [slot][j][b][64]
  float* cbuf = (float*)alloc((size_t)3*BB*DD*4);
  float* dbuf = (float*)alloc((size_t)3*BB*KK*4);
  float* biasg= (float*)alloc((size_t)3*2048*4);
  if (used > ws_size) { fprintf(stderr, "ws too small: need %zu have %zu\n", used, ws_size); return; }

  const long SZG = (long)BB*2048;
  const long SZR = (long)BB*64;

  auto slotg = [&](int s, int l){ return accg + (long)((s&3)*3+l)*SZG; };
  auto slotr = [&](int s, int l){ return accr + (long)((s&3)*3+l)*SZR; };
  auto slotu = [&](int s, int j){ return ubuf + (long)((s&3)*2+j)*SZR; };

  // ---- setup
  {
    long tot = (long)TT*BB*CC;
    k_xconv<<<dim3((tot + 255)/256), 256, 0, stream>>>(inputs, xb);
  }
  auto tp = [&](const float* src, long row_off, long srow, bf16* dstbase, long colbase, int N, int K){
    long total = (long)N*K;
    k_tpose<<<dim3((total + 255)/256), 256, 0, stream>>>(src + row_off*srow, srow, dstbase + colbase*K, K, total);
  };
  // BXT cols: [Wx0|Wr0|Wx1|Wr1|Wx2|Wr2] (first C=512 rows of each)
  tp(wx_w[0],0,2048, BXT,0,2048,512);   tp(wr_w[0],0,64, BXT,2048,64,512);
  tp(wx_w[1],0,2048, BXT,2112,2048,512);tp(wr_w[1],0,64, BXT,4160,64,512);
  tp(wx_w[2],0,2048, BXT,4224,2048,512);tp(wr_w[2],0,64, BXT,6272,64,512);
  // BG0T cols: [Wx1.h0|Wr1.h0|Wx2.h0|Wr2.h0|Wh0|Wl0]
  tp(wx_w[1],512,2048, BG0T,0,2048,512);   tp(wr_w[1],512,64, BG0T,2048,64,512);
  tp(wx_w[2],512,2048, BG0T,2112,2048,512);tp(wr_w[2],512,64, BG0T,4160,64,512);
  tp(wh_w[0],0,2048,   BG0T,4224,2048,512);tp(wl_w[0],0,64,   BG0T,6272,64,512);
  // BG1T cols: [Wx2.h1|Wr2.h1|Wh1|Wl1]
  tp(wx_w[2],1024,2048, BG1T,0,2048,512);  tp(wr_w[2],1024,64, BG1T,2048,64,512);
  tp(wh_w[1],0,2048,    BG1T,2112,2048,512);tp(wl_w[1],0,64,   BG1T,4160,64,512);
  // BG2T: [Wh2]
  tp(wh_w[2],0,2048, BG2T,0,2048,512);
  // projT
  tp(proj_w,0,512, projT,0,512,1536);

  k_bias<<<dim3(24),256,0,stream>>>(wx_b[0],wh_b[0],wx_b[1],wh_b[1],wx_b[2],wh_b[2], biasg);
  hipMemsetAsync(ubuf, 0, (size_t)4*2*BB*64*4, stream);
  hipMemsetAsync(cbuf, 0, (size_t)3*BB*DD*4, stream);
  k_dinit<<<dim3((3*BB*KK + 255)/256),256,0,stream>>>(init_keys, dbuf);

  // ---- pipelined recurrence: A(t) = {E0(t),E1(t-1),E2(t-2)}, B(t) = {I(t+2),G0(t),G1(t-1),G2(t-2)}
  for (int t = -2; t <= TT + 1; ++t) {
    // ----- A phase (one batched cell launch)
    CArgs ca{}; ca.n = 0;
    auto addE = [&](int s, int l){
      CellDesc& e = ca.e[ca.n++];
      e.gate = slotg(s,l); e.gr = slotr(s,l);
      e.u0 = (l>=1) ? slotu(s-1,0) : nullptr;
      e.u1 = (l>=2) ? slotu(s-1,1) : nullptr;
      e.c = cbuf + (long)l*BB*DD; e.d = dbuf + (long)l*BB*KK;
      e.hout = Hall + (long)s*1536 + (long)l*512;
    };
    if (t   >= 0 && t   < TT) addE(t,   0);
    if (t-1 >= 0 && t-1 < TT) addE(t-1, 1);
    if (t-2 >= 0 && t-2 < TT) addE(t-2, 2);
    if (ca.n)
      cell_batched<<<dim3(64, ca.n), 256, 0, stream>>>(ca, wd_w);

    // ----- B phase (one batched GEMM launch)
    GArgs ga{}; ga.ng = 0; ga.K = 512;
    int cursor = 0;
    auto addG = [&](const bf16* A, long lda, const bf16* Bm, int N, SegList sl){
      GDesc& g = ga.g[ga.ng++];
      g.A = A; g.lda = lda; g.B = Bm; g.ldb = 512;
      g.mtiles = 8; g.ntiles = N/64; g.tile_beg = cursor;
      cursor += g.mtiles * g.ntiles;
      g.segs = sl;
    };
    if (t+2 >= 0 && t+2 < TT) {  // I(t+2)
      int s = t+2;
      SegList sl{}; sl.n = 6;
      sl.s[0] = { slotg(s,0), 2048,    0, 0, biasg + 0    };
      sl.s[1] = { slotr(s,0),   64, 2048, 0, nullptr      };
      sl.s[2] = { slotg(s,1), 2048, 2112, 0, biasg + 2048 };
      sl.s[3] = { slotr(s,1),   64, 4160, 0, nullptr      };
      sl.s[4] = { slotg(s,2), 2048, 4224, 0, biasg + 4096 };
      sl.s[5] = { slotr(s,2),   64, 6272, 0, nullptr      };
      addG(xb + (long)s*BB*CC, 512, BXT, 6336, sl);
    }
    if (t >= 0 && t < TT) {      // G0(t)
      int s = t;
      SegList sl{}; sl.n = 6;
      sl.s[0] = { slotg(s,1),   2048,    0, 1, nullptr };
      sl.s[1] = { slotr(s,1),     64, 2048, 1, nullptr };
      sl.s[2] = { slotg(s,2),   2048, 2112, 1, nullptr };
      sl.s[3] = { slotr(s,2),     64, 4160, 1, nullptr };
      sl.s[4] = { slotg(s+1,0), 2048, 4224, 1, nullptr };  // Wh0 -> gate0(t+1)
      sl.s[5] = { slotu(s,0),     64, 6272, 0, nullptr };  // u0 = h0@Wl0
      addG(Hall + (long)s*1536, LDH, BG0T, 6336, sl);
    }
    if (t-1 >= 0 && t-1 < TT) {  // G1(t-1)
      int s = t-1;
      SegList sl{}; sl.n = 4;
      sl.s[0] = { slotg(s,2),   2048,    0, 1, nullptr };
      sl.s[1] = { slotr(s,2),     64, 2048, 1, nullptr };
      sl.s[2] = { slotg(s+1,1), 2048, 2112, 1, nullptr };  // Wh1 -> gate1(s+1)
      sl.s[3] = { slotu(s,1),     64, 4160, 0, nullptr };  // u1 = h1@Wl1
      addG(Hall + (long)s*1536 + 512, LDH, BG1T, 4224, sl);
    }
    if (t-2 >= 0 && t-2 <= TT-2) {  // G2(t-2), only needed for s <= 53
      int s = t-2;
      SegList sl{}; sl.n = 1;
      sl.s[0] = { slotg(s+1,2), 2048, 0, 1, nullptr };     // Wh2 -> gate2(s+1)
      addG(Hall + (long)s*1536 + 1024, LDH, BG2T, 2048, sl);
    }
    if (cursor)
      gemm_batched<<<dim3(cursor), 256, 0, stream>>>(ga);
  }

  // ---- projection: out[b][t][:] = Hall[b][t][:] @ proj + proj_b
  {
    GArgs ga{}; ga.ng = 1; ga.K = 1536;
    GDesc& g = ga.g[0];
    g.A = Hall; g.lda = 1536; g.B = projT; g.ldb = 1536;
    g.mtiles = (BB*TT)/64; g.ntiles = 512/64; g.tile_beg = 0;
    g.segs.n = 1;
    g.segs.s[0] = { out, 512, 0, 0, proj_b };
    gemm_batched<<<dim3(g.mtiles * g.ntiles), 256, 0, stream>>>(ga);
  }
}